// Round 13
// baseline (488.238 us; speedup 1.0000x reference)
//
#include <hip/hip_runtime.h>
#include <math.h>

#define HN 512   // hidden states
#define HM 4096  // emission symbols
#define HB 64    // batch
#define HT 512   // max seq len

// ---- 4-bit dot path (encoding must match between prep + fwd) ----
#if __has_builtin(__builtin_amdgcn_udot8)
  #define ENC_BIASED 0
  __device__ __forceinline__ int dot8q(unsigned int a, unsigned int b, int c){
    return (int)__builtin_amdgcn_udot8(a, b, (unsigned int)c, false);
  }
#elif __has_builtin(__builtin_amdgcn_sdot8)
  #define ENC_BIASED 1
  __device__ __forceinline__ int dot8q(unsigned int a, unsigned int b, int c){
    return __builtin_amdgcn_sdot8((int)a, (int)b, c, false);
  }
#else
  #define ENC_BIASED 0
  __device__ __forceinline__ int dot4u8f(unsigned int a, unsigned int b, int c){
#if __has_builtin(__builtin_amdgcn_sdot4)
    return __builtin_amdgcn_sdot4((int)a, (int)b, c, false);   // vals<=15, sign-safe
#else
    c += (int)(a & 0xffu)       * (int)(b & 0xffu);
    c += (int)((a>>8) & 0xffu)  * (int)((b>>8) & 0xffu);
    c += (int)((a>>16) & 0xffu) * (int)((b>>16) & 0xffu);
    c += (int)(a>>24)           * (int)(b>>24);
    return c;
#endif
  }
  __device__ __forceinline__ int dot8q(unsigned int a, unsigned int b, int c){
    unsigned int al = a & 0x0F0F0F0Fu, ah = (a>>4) & 0x0F0F0F0Fu;
    unsigned int bl = b & 0x0F0F0F0Fu, bh = (b>>4) & 0x0F0F0F0Fu;
    c = dot4u8f(al, bl, c);
    return dot4u8f(ah, bh, c);
  }
#endif

__device__ __forceinline__ float rcpf(float x){
#if __has_builtin(__builtin_amdgcn_rcpf)
  return __builtin_amdgcn_rcpf(x);
#else
  return 1.0f / x;
#endif
}

__device__ __forceinline__ float wsum(float v){
  #pragma unroll
  for(int o=32;o>0;o>>=1) v += __shfl_xor(v,o,64);
  return v;
}
__device__ __forceinline__ float wmax(float v){
  #pragma unroll
  for(int o=32;o>0;o>>=1) v = fmaxf(v,__shfl_xor(v,o,64));
  return v;
}

// ---- DPP wave64 reductions (VALU-latency, not DS-pipe) ----
#if __has_builtin(__builtin_amdgcn_update_dpp) && __has_builtin(__builtin_amdgcn_readlane)
#define HAVE_DPP 1
#define DPPF(v, ctrl, rmask) \
  __int_as_float(__builtin_amdgcn_update_dpp(0, __float_as_int(v), (ctrl), (rmask), 0xf, true))
__device__ __forceinline__ float wsum_nn(float v){   // sum of nonneg, result uniform
  v += DPPF(v, 0x111, 0xf);   // row_shr:1
  v += DPPF(v, 0x112, 0xf);   // row_shr:2
  v += DPPF(v, 0x114, 0xf);   // row_shr:4
  v += DPPF(v, 0x118, 0xf);   // row_shr:8
  v += DPPF(v, 0x142, 0xa);   // row_bcast:15 -> rows 1,3
  v += DPPF(v, 0x143, 0xc);   // row_bcast:31 -> rows 2,3
  return __int_as_float(__builtin_amdgcn_readlane(__float_as_int(v), 63));
}
__device__ __forceinline__ float wmax_nn(float v){   // max of nonneg, result uniform
  v = fmaxf(v, DPPF(v, 0x111, 0xf));
  v = fmaxf(v, DPPF(v, 0x112, 0xf));
  v = fmaxf(v, DPPF(v, 0x114, 0xf));
  v = fmaxf(v, DPPF(v, 0x118, 0xf));
  v = fmaxf(v, DPPF(v, 0x142, 0xa));
  v = fmaxf(v, DPPF(v, 0x143, 0xc));
  return __int_as_float(__builtin_amdgcn_readlane(__float_as_int(v), 63));
}
__device__ __forceinline__ int xor1_i(int v){        // lane^1 exchange, quad_perm [1,0,3,2]
  return __builtin_amdgcn_update_dpp(0, v, 0x0B1, 0xf, 0xf, true);
}
#else
#define HAVE_DPP 0
__device__ __forceinline__ float wsum_nn(float v){ return wsum(v); }
__device__ __forceinline__ float wmax_nn(float v){ return wmax(v); }
__device__ __forceinline__ int xor1_i(int v){ return __shfl_xor(v, 1, 64); }
#endif

__device__ __forceinline__ float blockSum512(float v, float* red, float* bc){
  v = wsum(v);
  if((threadIdx.x & 63)==0) red[threadIdx.x>>6] = v;
  __syncthreads();
  if(threadIdx.x < 64){
    float s = (threadIdx.x<8)? red[threadIdx.x] : 0.0f;
    #pragma unroll
    for(int o=4;o>0;o>>=1) s += __shfl_xor(s,o,64);
    if(threadIdx.x==0) *bc = s;
  }
  __syncthreads();
  return *bc;
}
__device__ __forceinline__ float blockMax512(float v, float* red, float* bc){
  v = wmax(v);
  if((threadIdx.x & 63)==0) red[threadIdx.x>>6] = v;
  __syncthreads();
  if(threadIdx.x < 64){
    float s = (threadIdx.x<8)? red[threadIdx.x] : -INFINITY;
    #pragma unroll
    for(int o=4;o>0;o>>=1) s = fmaxf(s, __shfl_xor(s,o,64));
    if(threadIdx.x==0) *bc = s;
  }
  __syncthreads();
  return *bc;
}

__device__ __forceinline__ unsigned short f2bf(float f){
  unsigned int u = __float_as_uint(f);
  unsigned int r = (u + 0x7fffu + ((u>>16)&1u)) >> 16;  // RNE
  return (unsigned short)r;
}
__device__ __forceinline__ float bf2f(unsigned int w){ return __uint_as_float(w<<16); }

// ---------------- prep kernels (fused: 2 launches, R11 verified) ----------------
// launch A: blocks [0,512) = em_lse rows ; [512,1024) = trcol cols (+prior)
// launch B: blocks [0,512) = trrow rows  ; [512,1024) = em_tab 64x64 tiles
// deps respected across the A->B boundary (trrow needs trcol, em_tab needs em_lse).

__global__ __launch_bounds__(512) void k_prepA(const float* __restrict__ em, float* __restrict__ em_lse,
                                               const float* __restrict__ tr,
                                               float* __restrict__ cmax, float* __restrict__ csum,
                                               const float* __restrict__ pri,
                                               float* __restrict__ P, float* __restrict__ pric){
  __shared__ float red[8]; __shared__ float bc;
  if(blockIdx.x < 512){
    int r = blockIdx.x;
    const float* row = em + (size_t)r*HM;
    float mx = -INFINITY;
    for(int i=threadIdx.x;i<HM;i+=512) mx = fmaxf(mx, row[i]);
    mx = blockMax512(mx, red, &bc);
    float s = 0.f;
    for(int i=threadIdx.x;i<HM;i+=512) s += expf(row[i]-mx);
    s = blockSum512(s, red, &bc);
    if(threadIdx.x==0) em_lse[r] = mx + logf(s);
  } else {
    int k = blockIdx.x - 512, j = threadIdx.x;
    float v = tr[(size_t)j*HN + k];
    float mx = blockMax512(v, red, &bc);
    float s  = blockSum512(expf(v-mx), red, &bc);
    if(j==0){ cmax[k] = mx; csum[k] = s; }
    if(k == 0){
      float pv = pri[j];
      float pmx = blockMax512(pv, red, &bc);
      float pw = expf(pv-pmx);
      float ps = blockSum512(pw, red, &bc);
      P[j] = pw;
      if(j==0) *pric = -logf(ps);
    }
  }
}

__global__ __launch_bounds__(512) void k_prepB(const float* __restrict__ tr,
                                               const float* __restrict__ cmax, const float* __restrict__ csum,
                                               unsigned char* __restrict__ TQ4,
                                               float* __restrict__ rscale, float* __restrict__ rbar,
                                               unsigned short* __restrict__ tsumq,
                                               const float* __restrict__ em, const float* __restrict__ em_lse,
                                               unsigned short* __restrict__ emT){
  __shared__ float red[8]; __shared__ float bc;
  __shared__ unsigned short tile[64][66];
  __shared__ float lsl[64];
  if(blockIdx.x < 512){
    int j = blockIdx.x, k = threadIdx.x;
    float v = expf(tr[(size_t)j*HN + k] - cmax[k]) / csum[k];
    float rm = blockMax512(v, red, &bc);
    int q = __float2int_rn(v * (15.0f/rm));          // 0..15
    float rs = blockSum512(v, red, &bc);             // true row sum
    float qs = blockSum512((float)q, red, &bc);      // total q sum
    float wq = wsum((float)q);                       // per-wave(64k) q sum
    int qn = __shfl_down(q, 1, 64);
    if((k & 1)==0){
#if ENC_BIASED
      unsigned char by = (unsigned char)(((q-8)&0xF) | (((qn-8)&0xF)<<4));
#else
      unsigned char by = (unsigned char)((q&0xF) | ((qn&0xF)<<4));
#endif
      TQ4[(size_t)j*256 + ((k>>5)<<4) + ((k&31)>>1)] = by;
    }
    if((k&63)==0) tsumq[j*8 + (k>>6)] = (unsigned short)(int)wq;
    if(k==0){
      rscale[j] = rm * (1.0f/15.0f);
      rbar[j]   = rs - (rm * (1.0f/15.0f)) * qs;
    }
  } else {
    int q = blockIdx.x - 512;                    // 512 tiles = 64 m-tiles x 8 j-tiles
    int m0 = (q & 63)*64, j0 = (q >> 6)*64;
    int tx = threadIdx.x & 63, ty = threadIdx.x >> 6;   // ty in [0,8)
    if(threadIdx.x < 64) lsl[threadIdx.x] = em_lse[j0 + threadIdx.x];
    __syncthreads();
    #pragma unroll
    for(int r=0;r<8;r++){
      int jl = ty*8 + r;
      float v = em[(size_t)(j0+jl)*HM + m0 + tx];
      tile[jl][tx] = f2bf(expf(v - lsl[jl]));
    }
    __syncthreads();
    #pragma unroll
    for(int r=0;r<8;r++){
      int ml = ty*8 + r;
      emT[(size_t)(m0+ml)*HN + j0 + tx] = tile[tx][ml];
    }
  }
}

// ---------------- forward recurrence (R9/R11 best: 421us, VGPR 48) ----------
// 64 blocks (1/batch), 512 threads = 8 waves. ONE barrier/step, ping-pong
// alpha/stats planes, stale-S normalizer, wave-local DPP finalize, Tr via
// scratch stream (the measured L1 floor: 128 KB/step at ~64 B/cyc = 1960
// cyc/step at 2.7% occupancy).
// SESSION LEDGER (R1-R12): every relocation of the Tr stream lost --
// LDS (R5: +DS-pipe serialization), AGPR (R3/R6/R7: volatile-asm ordering /
// SGPR-readlane hazard / pipeline blocking), named regs (R2/R9: allocator
// spills loop-long values regardless of launch-bounds hints), pipe-splits
// (R8/R10: vmem/DS refuse to overlap at 2 waves/SIMD, any VGPR budget).
// R12's 2-blocks-per-batch mailbox (the only path below this floor: halve
// the per-CU stream) hung the container twice -> reverted per pre-registered
// tell. Do NOT retry without interactive hang debugging (suspects: byte
// atomic-store CAS lowering; relaxed agent-scope spin visibility).
__global__ __launch_bounds__(512, 1)
void k_fwd(const int* __restrict__ x, const int* __restrict__ Tl,
           const unsigned short* __restrict__ emTu,
           const float* __restrict__ P, const float* __restrict__ pric,
           const float* __restrict__ rscaleG, const float* __restrict__ rbarG,
           const unsigned short* __restrict__ tsumqG,
           const uint4* __restrict__ TQd4,
           float* __restrict__ out){
  extern __shared__ char smem[];
  uint4*         apl4  = (uint4*)smem;                         // [2][16] uint4 = 512 B
  unsigned char* aplB  = (unsigned char*)smem;
  float*         sigS  = (float*)(smem + 512);                 // [2][8]
  float*         sumS  = (float*)(smem + 576);                 // [2][8]
  float*         aqS   = (float*)(smem + 640);                 // [2][8]
  float*         rawS  = (float*)(smem + 704);                 // [8]
  int*           xls   = (int*)(smem + 768);                   // 2048
  float*         rscL  = (float*)(smem + 2816);                // 2048
  float*         rbarL = (float*)(smem + 4864);                // 2048
  unsigned short* tsumL= (unsigned short*)(smem + 6912);       // 8192
  // total 15104 B

  const int t = threadIdx.x, b = blockIdx.x, w = t>>6, L = t&63;
  const int j = t;

  const uint4* trp = TQd4 + (size_t)j*16;
  unsigned int trq[48];
  #pragma unroll
  for(int q=0;q<12;q++) ((uint4*)trq)[q] = trp[q];
  #pragma unroll
  for(int r=0;r<48;r++) asm volatile("" : "+v"(trq[r]));
  uint4 c12 = trp[12], c13 = trp[13], c14 = trp[14], c15 = trp[15];

  xls[t]   = x[b*HT + t];
  rscL[t]  = rscaleG[t];
  rbarL[t] = rbarG[t];
  for(int d=t; d<2048; d+=512) ((unsigned int*)tsumL)[d] = ((const unsigned int*)tsumqG)[d];
  int Tb = Tl[b];
  __syncthreads();

  // ---- init (t = 0) ----
  int m = xls[0];
  float e0 = bf2f((unsigned)emTu[(size_t)m*HN + j]);
  float nvr = e0 * P[j];
  {
    float s = wsum_nn(nvr);
    if(L==0) rawS[w] = s;
  }
  __syncthreads();
  float4 q0 = ((float4*)rawS)[0], q1 = ((float4*)rawS)[1];
  float S0 = ((q0.x+q0.y)+(q0.z+q0.w))+((q1.x+q1.y)+(q1.z+q1.w));
  float c_acc = pric[0] + __logf(S0);
  float nvd = nvr * rcpf(S0);
  {
    float Mw = fmaxf(wmax_nn(nvd), 1e-30f);
    float sig = Mw * (1.0f/15.0f);
    int aq = __float2int_rn(nvd * (15.0f * rcpf(Mw)));
    float Sw = wsum_nn(nvd);
#if ENC_BIASED
    float AqSw = wsum_nn((float)aq);
#endif
    int aqn = xor1_i(aq);
    if((j&1)==0){
#if ENC_BIASED
      aplB[256 + (j>>1)] = (unsigned char)(((aq-8)&0xF) | (((aqn-8)&0xF)<<4));
#else
      aplB[256 + (j>>1)] = (unsigned char)((aq&0xF) | ((aqn&0xF)<<4));
#endif
    }
    if(L==0){
      sigS[8+w] = sig; sumS[8+w] = Sw;
#if ENC_BIASED
      aqS[8+w] = AqSw;
#endif
    }
  }
  int mn = xls[(Tb>1)?1:0];
  float eC = bf2f((unsigned)emTu[(size_t)mn*HN + j]);
  const float rsc = rscL[j], rbr = rbarL[j];

  for(int tt=1; tt<Tb; tt++){
    __syncthreads();                      // the ONE barrier per step
    const int rb = (tt & 1), wb = rb ^ 1;

    // [a] full-row dot: 16 alpha chunks (wave-uniform b128 broadcast);
    //     Tr chunks 0..11 from scratch (vmem pipe), 12..15 from registers
    int acc[8];
    #pragma unroll
    for(int i=0;i<8;i++) acc[i] = 0;
    const uint4* aplR = apl4 + 16*rb;
    #pragma unroll
    for(int c=0;c<12;c++){
      uint4 A = aplR[c];
      int wi = c>>1;
      acc[wi] = dot8q(trq[4*c+0], A.x, acc[wi]);
      acc[wi] = dot8q(trq[4*c+1], A.y, acc[wi]);
      acc[wi] = dot8q(trq[4*c+2], A.z, acc[wi]);
      acc[wi] = dot8q(trq[4*c+3], A.w, acc[wi]);
    }
    {
      uint4 A = aplR[12];
      acc[6] = dot8q(c12.x, A.x, acc[6]);
      acc[6] = dot8q(c12.y, A.y, acc[6]);
      acc[6] = dot8q(c12.z, A.z, acc[6]);
      acc[6] = dot8q(c12.w, A.w, acc[6]);
      A = aplR[13];
      acc[6] = dot8q(c13.x, A.x, acc[6]);
      acc[6] = dot8q(c13.y, A.y, acc[6]);
      acc[6] = dot8q(c13.z, A.z, acc[6]);
      acc[6] = dot8q(c13.w, A.w, acc[6]);
      A = aplR[14];
      acc[7] = dot8q(c14.x, A.x, acc[7]);
      acc[7] = dot8q(c14.y, A.y, acc[7]);
      acc[7] = dot8q(c14.z, A.z, acc[7]);
      acc[7] = dot8q(c14.w, A.w, acc[7]);
      A = aplR[15];
      acc[7] = dot8q(c15.x, A.x, acc[7]);
      acc[7] = dot8q(c15.y, A.y, acc[7]);
      acc[7] = dot8q(c15.z, A.z, acc[7]);
      acc[7] = dot8q(c15.w, A.w, acc[7]);
    }

    // [b] previous-step stats (uniform reads)
    float4 g0 = ((float4*)(sumS + 8*rb))[0], g1 = ((float4*)(sumS + 8*rb))[1];
    float Sp = ((g0.x+g0.y)+(g0.z+g0.w))+((g1.x+g1.y)+(g1.z+g1.w));
    if(tt > 1) c_acc += __logf(Sp);
    float d_inv = rcpf(Sp);
    float abar  = Sp * (1.0f/512.0f);
    float4 s0 = ((float4*)(sigS + 8*rb))[0], s1 = ((float4*)(sigS + 8*rb))[1];
    float sg[8] = {s0.x,s0.y,s0.z,s0.w,s1.x,s1.y,s1.z,s1.w};

    // [c] combine with per-slice alpha scales (+ sdot bias correction)
    float Af = 0.f;
#if ENC_BIASED
    {
      float4 a0 = ((float4*)(aqS + 8*rb))[0], a1 = ((float4*)(aqS + 8*rb))[1];
      float av[8] = {a0.x,a0.y,a0.z,a0.w,a1.x,a1.y,a1.z,a1.w};
      uint4 tq = ((const uint4*)tsumL)[j];
      int ts[8] = {(int)(tq.x&0xffff),(int)(tq.x>>16),(int)(tq.y&0xffff),(int)(tq.y>>16),
                   (int)(tq.z&0xffff),(int)(tq.z>>16),(int)(tq.w&0xffff),(int)(tq.w>>16)};
      #pragma unroll
      for(int i=0;i<8;i++)
        Af += sg[i] * (float)(acc[i] + 8*(ts[i] + (int)av[i]) - 4096);
    }
#else
    #pragma unroll
    for(int i=0;i<8;i++) Af += sg[i] * (float)acc[i];
#endif
    float D = rsc * Af + abar * rbr;
    nvd = fmaxf(D * eC * d_inv, 0.0f);

    // prefetch next emission
    int tn = (tt+1 < HT)? tt+1 : HT-1;
    mn = xls[tn];
    float eN = bf2f((unsigned)emTu[(size_t)mn*HN + j]);

    // [e] wave-local finalize: quantize vs wave max (DPP reduce), write plane wb
    float Mw = fmaxf(wmax_nn(nvd), 1e-30f);
    float sig = Mw * (1.0f/15.0f);
    int aq = __float2int_rn(nvd * (15.0f * rcpf(Mw)));
    float Sw = wsum_nn(nvd);
#if ENC_BIASED
    float AqSw = wsum_nn((float)aq);
#endif
    int aqn = xor1_i(aq);
    if((j&1)==0){
#if ENC_BIASED
      aplB[256*wb + (j>>1)] = (unsigned char)(((aq-8)&0xF) | (((aqn-8)&0xF)<<4));
#else
      aplB[256*wb + (j>>1)] = (unsigned char)((aq&0xF) | ((aqn&0xF)<<4));
#endif
    }
    if(L==0){
      sigS[8*wb+w] = sig; sumS[8*wb+w] = Sw;
#if ENC_BIASED
      aqS[8*wb+w] = AqSw;
#endif
    }
    eC = eN;
  }

  // ---- flush last step's S ----
  __syncthreads();
  {
    const int fb = (Tb & 1);
    float4 g0 = ((float4*)(sumS + 8*fb))[0], g1 = ((float4*)(sumS + 8*fb))[1];
    float Sf = ((g0.x+g0.y)+(g0.z+g0.w))+((g1.x+g1.y)+(g1.z+g1.w));
    if(t==0) out[b] = c_acc + __logf(Sf);
  }
}

extern "C" void kernel_launch(void* const* d_in, const int* in_sizes, int n_in,
                              void* d_out, int out_size, void* d_ws, size_t ws_size,
                              hipStream_t stream){
  const int*   x   = (const int*)d_in[0];
  const int*   T   = (const int*)d_in[1];
  const float* em  = (const float*)d_in[2];
  const float* tr  = (const float*)d_in[3];
  const float* pri = (const float*)d_in[4];
  float* out = (float*)d_out;

  char* ws = (char*)d_ws;
  float* em_lse = (float*)ws;                                   // 2 KiB
  float* P      = (float*)(ws + 2048);                          // 2 KiB
  float* pric   = (float*)(ws + 4096);                          // 16 B
  float* cmax   = (float*)(ws + 8192);                          // 2 KiB
  float* csum   = (float*)(ws + 10240);                         // 2 KiB
  float* rscale = (float*)(ws + 12288);                         // 2 KiB
  float* rbar   = (float*)(ws + 14336);                         // 2 KiB
  unsigned short* tsumq = (unsigned short*)(ws + 16384);        // 8 KiB
  unsigned short* emT = (unsigned short*)(ws + 24576);          // 4 MiB
  unsigned char*  TQ4 = (unsigned char*)(ws + 24576 + (size_t)HM*HN*2);  // 128 KiB

  k_prepA<<<1024, 512, 0, stream>>>(em, em_lse, tr, cmax, csum, pri, P, pric);
  k_prepB<<<1024, 512, 0, stream>>>(tr, cmax, csum, TQ4, rscale, rbar, tsumq,
                                    em, em_lse, emT);

  const int lds_bytes = 15104;
  (void)hipFuncSetAttribute((const void*)k_fwd, hipFuncAttributeMaxDynamicSharedMemorySize, lds_bytes);
  k_fwd<<<HB, 512, lds_bytes, stream>>>(x, T, emT, P, pric, rscale, rbar, tsumq,
                                        (const uint4*)TQ4, out);
}

// Round 14
// 484.164 us; speedup vs baseline: 1.0084x; 1.0084x over previous
//
#include <hip/hip_runtime.h>
#include <math.h>

#define HN 512   // hidden states
#define HM 4096  // emission symbols
#define HB 64    // batch
#define HT 512   // max seq len

// ---- 4-bit dot path (encoding must match between prep + fwd) ----
#if __has_builtin(__builtin_amdgcn_udot8)
  #define ENC_BIASED 0
  __device__ __forceinline__ int dot8q(unsigned int a, unsigned int b, int c){
    return (int)__builtin_amdgcn_udot8(a, b, (unsigned int)c, false);
  }
#elif __has_builtin(__builtin_amdgcn_sdot8)
  #define ENC_BIASED 1
  __device__ __forceinline__ int dot8q(unsigned int a, unsigned int b, int c){
    return __builtin_amdgcn_sdot8((int)a, (int)b, c, false);
  }
#else
  #define ENC_BIASED 0
  __device__ __forceinline__ int dot4u8f(unsigned int a, unsigned int b, int c){
#if __has_builtin(__builtin_amdgcn_sdot4)
    return __builtin_amdgcn_sdot4((int)a, (int)b, c, false);   // vals<=15, sign-safe
#else
    c += (int)(a & 0xffu)       * (int)(b & 0xffu);
    c += (int)((a>>8) & 0xffu)  * (int)((b>>8) & 0xffu);
    c += (int)((a>>16) & 0xffu) * (int)((b>>16) & 0xffu);
    c += (int)(a>>24)           * (int)(b>>24);
    return c;
#endif
  }
  __device__ __forceinline__ int dot8q(unsigned int a, unsigned int b, int c){
    unsigned int al = a & 0x0F0F0F0Fu, ah = (a>>4) & 0x0F0F0F0Fu;
    unsigned int bl = b & 0x0F0F0F0Fu, bh = (b>>4) & 0x0F0F0F0Fu;
    c = dot4u8f(al, bl, c);
    return dot4u8f(ah, bh, c);
  }
#endif

__device__ __forceinline__ float rcpf(float x){
#if __has_builtin(__builtin_amdgcn_rcpf)
  return __builtin_amdgcn_rcpf(x);
#else
  return 1.0f / x;
#endif
}

__device__ __forceinline__ float wsum(float v){
  #pragma unroll
  for(int o=32;o>0;o>>=1) v += __shfl_xor(v,o,64);
  return v;
}
__device__ __forceinline__ float wmax(float v){
  #pragma unroll
  for(int o=32;o>0;o>>=1) v = fmaxf(v,__shfl_xor(v,o,64));
  return v;
}

// ---- DPP wave64 reductions (VALU-latency, not DS-pipe) ----
#if __has_builtin(__builtin_amdgcn_update_dpp) && __has_builtin(__builtin_amdgcn_readlane)
#define HAVE_DPP 1
#define DPPF(v, ctrl, rmask) \
  __int_as_float(__builtin_amdgcn_update_dpp(0, __float_as_int(v), (ctrl), (rmask), 0xf, true))
__device__ __forceinline__ float wsum_nn(float v){   // sum of nonneg, result uniform
  v += DPPF(v, 0x111, 0xf);   // row_shr:1
  v += DPPF(v, 0x112, 0xf);   // row_shr:2
  v += DPPF(v, 0x114, 0xf);   // row_shr:4
  v += DPPF(v, 0x118, 0xf);   // row_shr:8
  v += DPPF(v, 0x142, 0xa);   // row_bcast:15 -> rows 1,3
  v += DPPF(v, 0x143, 0xc);   // row_bcast:31 -> rows 2,3
  return __int_as_float(__builtin_amdgcn_readlane(__float_as_int(v), 63));
}
__device__ __forceinline__ float wmax_nn(float v){   // max of nonneg, result uniform
  v = fmaxf(v, DPPF(v, 0x111, 0xf));
  v = fmaxf(v, DPPF(v, 0x112, 0xf));
  v = fmaxf(v, DPPF(v, 0x114, 0xf));
  v = fmaxf(v, DPPF(v, 0x118, 0xf));
  v = fmaxf(v, DPPF(v, 0x142, 0xa));
  v = fmaxf(v, DPPF(v, 0x143, 0xc));
  return __int_as_float(__builtin_amdgcn_readlane(__float_as_int(v), 63));
}
__device__ __forceinline__ int xor1_i(int v){        // lane^1 exchange, quad_perm [1,0,3,2]
  return __builtin_amdgcn_update_dpp(0, v, 0x0B1, 0xf, 0xf, true);
}
#else
#define HAVE_DPP 0
__device__ __forceinline__ float wsum_nn(float v){ return wsum(v); }
__device__ __forceinline__ float wmax_nn(float v){ return wmax(v); }
__device__ __forceinline__ int xor1_i(int v){ return __shfl_xor(v, 1, 64); }
#endif

__device__ __forceinline__ float blockSum512(float v, float* red, float* bc){
  v = wsum(v);
  if((threadIdx.x & 63)==0) red[threadIdx.x>>6] = v;
  __syncthreads();
  if(threadIdx.x < 64){
    float s = (threadIdx.x<8)? red[threadIdx.x] : 0.0f;
    #pragma unroll
    for(int o=4;o>0;o>>=1) s += __shfl_xor(s,o,64);
    if(threadIdx.x==0) *bc = s;
  }
  __syncthreads();
  return *bc;
}
__device__ __forceinline__ float blockMax512(float v, float* red, float* bc){
  v = wmax(v);
  if((threadIdx.x & 63)==0) red[threadIdx.x>>6] = v;
  __syncthreads();
  if(threadIdx.x < 64){
    float s = (threadIdx.x<8)? red[threadIdx.x] : -INFINITY;
    #pragma unroll
    for(int o=4;o>0;o>>=1) s = fmaxf(s, __shfl_xor(s,o,64));
    if(threadIdx.x==0) *bc = s;
  }
  __syncthreads();
  return *bc;
}

__device__ __forceinline__ unsigned short f2bf(float f){
  unsigned int u = __float_as_uint(f);
  unsigned int r = (u + 0x7fffu + ((u>>16)&1u)) >> 16;  // RNE
  return (unsigned short)r;
}
__device__ __forceinline__ float bf2f(unsigned int w){ return __uint_as_float(w<<16); }

// ---------------- prep kernels (fused: 2 launches, R11 verified) ----------------
// launch A: blocks [0,512) = em_lse rows ; [512,1024) = trcol cols (+prior)
// launch B: blocks [0,512) = trrow rows  ; [512,1024) = em_tab 64x64 tiles
// deps respected across the A->B boundary (trrow needs trcol, em_tab needs em_lse).
// ROUND 14: em_lse now SINGLE memory pass -- the 8 per-thread values are held
// in registers between the max and sum phases (same elements, same per-thread
// fold order, same reduction trees => bit-identical result; deletes the second
// 8 MB traversal). Everything else verbatim R13.

__global__ __launch_bounds__(512) void k_prepA(const float* __restrict__ em, float* __restrict__ em_lse,
                                               const float* __restrict__ tr,
                                               float* __restrict__ cmax, float* __restrict__ csum,
                                               const float* __restrict__ pri,
                                               float* __restrict__ P, float* __restrict__ pric){
  __shared__ float red[8]; __shared__ float bc;
  if(blockIdx.x < 512){
    int r = blockIdx.x;
    const float* row = em + (size_t)r*HM;
    // single pass: load the 8 strided elements once (same mapping as the old
    // i=t; i<HM; i+=512 loop), keep in registers for both reductions
    float v0 = row[threadIdx.x +    0];
    float v1 = row[threadIdx.x +  512];
    float v2 = row[threadIdx.x + 1024];
    float v3 = row[threadIdx.x + 1536];
    float v4 = row[threadIdx.x + 2048];
    float v5 = row[threadIdx.x + 2560];
    float v6 = row[threadIdx.x + 3072];
    float v7 = row[threadIdx.x + 3584];
    float mx = -INFINITY;
    mx = fmaxf(mx, v0); mx = fmaxf(mx, v1); mx = fmaxf(mx, v2); mx = fmaxf(mx, v3);
    mx = fmaxf(mx, v4); mx = fmaxf(mx, v5); mx = fmaxf(mx, v6); mx = fmaxf(mx, v7);
    mx = blockMax512(mx, red, &bc);
    float s = 0.f;
    s += expf(v0-mx); s += expf(v1-mx); s += expf(v2-mx); s += expf(v3-mx);
    s += expf(v4-mx); s += expf(v5-mx); s += expf(v6-mx); s += expf(v7-mx);
    s = blockSum512(s, red, &bc);
    if(threadIdx.x==0) em_lse[r] = mx + logf(s);
  } else {
    int k = blockIdx.x - 512, j = threadIdx.x;
    float v = tr[(size_t)j*HN + k];
    float mx = blockMax512(v, red, &bc);
    float s  = blockSum512(expf(v-mx), red, &bc);
    if(j==0){ cmax[k] = mx; csum[k] = s; }
    if(k == 0){
      float pv = pri[j];
      float pmx = blockMax512(pv, red, &bc);
      float pw = expf(pv-pmx);
      float ps = blockSum512(pw, red, &bc);
      P[j] = pw;
      if(j==0) *pric = -logf(ps);
    }
  }
}

__global__ __launch_bounds__(512) void k_prepB(const float* __restrict__ tr,
                                               const float* __restrict__ cmax, const float* __restrict__ csum,
                                               unsigned char* __restrict__ TQ4,
                                               float* __restrict__ rscale, float* __restrict__ rbar,
                                               unsigned short* __restrict__ tsumq,
                                               const float* __restrict__ em, const float* __restrict__ em_lse,
                                               unsigned short* __restrict__ emT){
  __shared__ float red[8]; __shared__ float bc;
  __shared__ unsigned short tile[64][66];
  __shared__ float lsl[64];
  if(blockIdx.x < 512){
    int j = blockIdx.x, k = threadIdx.x;
    float v = expf(tr[(size_t)j*HN + k] - cmax[k]) / csum[k];
    float rm = blockMax512(v, red, &bc);
    int q = __float2int_rn(v * (15.0f/rm));          // 0..15
    float rs = blockSum512(v, red, &bc);             // true row sum
    float qs = blockSum512((float)q, red, &bc);      // total q sum
    float wq = wsum((float)q);                       // per-wave(64k) q sum
    int qn = __shfl_down(q, 1, 64);
    if((k & 1)==0){
#if ENC_BIASED
      unsigned char by = (unsigned char)(((q-8)&0xF) | (((qn-8)&0xF)<<4));
#else
      unsigned char by = (unsigned char)((q&0xF) | ((qn&0xF)<<4));
#endif
      TQ4[(size_t)j*256 + ((k>>5)<<4) + ((k&31)>>1)] = by;
    }
    if((k&63)==0) tsumq[j*8 + (k>>6)] = (unsigned short)(int)wq;
    if(k==0){
      rscale[j] = rm * (1.0f/15.0f);
      rbar[j]   = rs - (rm * (1.0f/15.0f)) * qs;
    }
  } else {
    int q = blockIdx.x - 512;                    // 512 tiles = 64 m-tiles x 8 j-tiles
    int m0 = (q & 63)*64, j0 = (q >> 6)*64;
    int tx = threadIdx.x & 63, ty = threadIdx.x >> 6;   // ty in [0,8)
    if(threadIdx.x < 64) lsl[threadIdx.x] = em_lse[j0 + threadIdx.x];
    __syncthreads();
    #pragma unroll
    for(int r=0;r<8;r++){
      int jl = ty*8 + r;
      float v = em[(size_t)(j0+jl)*HM + m0 + tx];
      tile[jl][tx] = f2bf(expf(v - lsl[jl]));
    }
    __syncthreads();
    #pragma unroll
    for(int r=0;r<8;r++){
      int ml = ty*8 + r;
      emT[(size_t)(m0+ml)*HN + j0 + tx] = tile[tx][ml];
    }
  }
}

// ---------------- forward recurrence (R9/R11 best: 421us, VGPR 48) ----------
// 64 blocks (1/batch), 512 threads = 8 waves. ONE barrier/step, ping-pong
// alpha/stats planes, stale-S normalizer, wave-local DPP finalize, Tr via
// scratch stream (the measured L1 floor: 128 KB/step at ~64 B/cyc = 1960
// cyc/step at 2.7% occupancy).
// SESSION LEDGER (R1-R13): every relocation of the Tr stream lost --
// LDS (R5: +DS-pipe serialization), AGPR (R3/R6/R7: volatile-asm ordering /
// SGPR-readlane hazard / pipeline blocking), named regs (R2/R9: allocator
// spills loop-long values regardless of launch-bounds hints), pipe-splits
// (R8/R10: vmem/DS refuse to overlap at 2 waves/SIMD, any VGPR budget).
// R12's 2-blocks-per-batch mailbox (the only path below this floor: halve
// the per-CU stream) hung the container twice -> reverted per pre-registered
// tell. Do NOT retry without interactive hang debugging (suspects: byte
// atomic-store CAS lowering; relaxed agent-scope spin visibility).
__global__ __launch_bounds__(512, 1)
void k_fwd(const int* __restrict__ x, const int* __restrict__ Tl,
           const unsigned short* __restrict__ emTu,
           const float* __restrict__ P, const float* __restrict__ pric,
           const float* __restrict__ rscaleG, const float* __restrict__ rbarG,
           const unsigned short* __restrict__ tsumqG,
           const uint4* __restrict__ TQd4,
           float* __restrict__ out){
  extern __shared__ char smem[];
  uint4*         apl4  = (uint4*)smem;                         // [2][16] uint4 = 512 B
  unsigned char* aplB  = (unsigned char*)smem;
  float*         sigS  = (float*)(smem + 512);                 // [2][8]
  float*         sumS  = (float*)(smem + 576);                 // [2][8]
  float*         aqS   = (float*)(smem + 640);                 // [2][8]
  float*         rawS  = (float*)(smem + 704);                 // [8]
  int*           xls   = (int*)(smem + 768);                   // 2048
  float*         rscL  = (float*)(smem + 2816);                // 2048
  float*         rbarL = (float*)(smem + 4864);                // 2048
  unsigned short* tsumL= (unsigned short*)(smem + 6912);       // 8192
  // total 15104 B

  const int t = threadIdx.x, b = blockIdx.x, w = t>>6, L = t&63;
  const int j = t;

  const uint4* trp = TQd4 + (size_t)j*16;
  unsigned int trq[48];
  #pragma unroll
  for(int q=0;q<12;q++) ((uint4*)trq)[q] = trp[q];
  #pragma unroll
  for(int r=0;r<48;r++) asm volatile("" : "+v"(trq[r]));
  uint4 c12 = trp[12], c13 = trp[13], c14 = trp[14], c15 = trp[15];

  xls[t]   = x[b*HT + t];
  rscL[t]  = rscaleG[t];
  rbarL[t] = rbarG[t];
  for(int d=t; d<2048; d+=512) ((unsigned int*)tsumL)[d] = ((const unsigned int*)tsumqG)[d];
  int Tb = Tl[b];
  __syncthreads();

  // ---- init (t = 0) ----
  int m = xls[0];
  float e0 = bf2f((unsigned)emTu[(size_t)m*HN + j]);
  float nvr = e0 * P[j];
  {
    float s = wsum_nn(nvr);
    if(L==0) rawS[w] = s;
  }
  __syncthreads();
  float4 q0 = ((float4*)rawS)[0], q1 = ((float4*)rawS)[1];
  float S0 = ((q0.x+q0.y)+(q0.z+q0.w))+((q1.x+q1.y)+(q1.z+q1.w));
  float c_acc = pric[0] + __logf(S0);
  float nvd = nvr * rcpf(S0);
  {
    float Mw = fmaxf(wmax_nn(nvd), 1e-30f);
    float sig = Mw * (1.0f/15.0f);
    int aq = __float2int_rn(nvd * (15.0f * rcpf(Mw)));
    float Sw = wsum_nn(nvd);
#if ENC_BIASED
    float AqSw = wsum_nn((float)aq);
#endif
    int aqn = xor1_i(aq);
    if((j&1)==0){
#if ENC_BIASED
      aplB[256 + (j>>1)] = (unsigned char)(((aq-8)&0xF) | (((aqn-8)&0xF)<<4));
#else
      aplB[256 + (j>>1)] = (unsigned char)((aq&0xF) | ((aqn&0xF)<<4));
#endif
    }
    if(L==0){
      sigS[8+w] = sig; sumS[8+w] = Sw;
#if ENC_BIASED
      aqS[8+w] = AqSw;
#endif
    }
  }
  int mn = xls[(Tb>1)?1:0];
  float eC = bf2f((unsigned)emTu[(size_t)mn*HN + j]);
  const float rsc = rscL[j], rbr = rbarL[j];

  for(int tt=1; tt<Tb; tt++){
    __syncthreads();                      // the ONE barrier per step
    const int rb = (tt & 1), wb = rb ^ 1;

    // [a] full-row dot: 16 alpha chunks (wave-uniform b128 broadcast);
    //     Tr chunks 0..11 from scratch (vmem pipe), 12..15 from registers
    int acc[8];
    #pragma unroll
    for(int i=0;i<8;i++) acc[i] = 0;
    const uint4* aplR = apl4 + 16*rb;
    #pragma unroll
    for(int c=0;c<12;c++){
      uint4 A = aplR[c];
      int wi = c>>1;
      acc[wi] = dot8q(trq[4*c+0], A.x, acc[wi]);
      acc[wi] = dot8q(trq[4*c+1], A.y, acc[wi]);
      acc[wi] = dot8q(trq[4*c+2], A.z, acc[wi]);
      acc[wi] = dot8q(trq[4*c+3], A.w, acc[wi]);
    }
    {
      uint4 A = aplR[12];
      acc[6] = dot8q(c12.x, A.x, acc[6]);
      acc[6] = dot8q(c12.y, A.y, acc[6]);
      acc[6] = dot8q(c12.z, A.z, acc[6]);
      acc[6] = dot8q(c12.w, A.w, acc[6]);
      A = aplR[13];
      acc[6] = dot8q(c13.x, A.x, acc[6]);
      acc[6] = dot8q(c13.y, A.y, acc[6]);
      acc[6] = dot8q(c13.z, A.z, acc[6]);
      acc[6] = dot8q(c13.w, A.w, acc[6]);
      A = aplR[14];
      acc[7] = dot8q(c14.x, A.x, acc[7]);
      acc[7] = dot8q(c14.y, A.y, acc[7]);
      acc[7] = dot8q(c14.z, A.z, acc[7]);
      acc[7] = dot8q(c14.w, A.w, acc[7]);
      A = aplR[15];
      acc[7] = dot8q(c15.x, A.x, acc[7]);
      acc[7] = dot8q(c15.y, A.y, acc[7]);
      acc[7] = dot8q(c15.z, A.z, acc[7]);
      acc[7] = dot8q(c15.w, A.w, acc[7]);
    }

    // [b] previous-step stats (uniform reads)
    float4 g0 = ((float4*)(sumS + 8*rb))[0], g1 = ((float4*)(sumS + 8*rb))[1];
    float Sp = ((g0.x+g0.y)+(g0.z+g0.w))+((g1.x+g1.y)+(g1.z+g1.w));
    if(tt > 1) c_acc += __logf(Sp);
    float d_inv = rcpf(Sp);
    float abar  = Sp * (1.0f/512.0f);
    float4 s0 = ((float4*)(sigS + 8*rb))[0], s1 = ((float4*)(sigS + 8*rb))[1];
    float sg[8] = {s0.x,s0.y,s0.z,s0.w,s1.x,s1.y,s1.z,s1.w};

    // [c] combine with per-slice alpha scales (+ sdot bias correction)
    float Af = 0.f;
#if ENC_BIASED
    {
      float4 a0 = ((float4*)(aqS + 8*rb))[0], a1 = ((float4*)(aqS + 8*rb))[1];
      float av[8] = {a0.x,a0.y,a0.z,a0.w,a1.x,a1.y,a1.z,a1.w};
      uint4 tq = ((const uint4*)tsumL)[j];
      int ts[8] = {(int)(tq.x&0xffff),(int)(tq.x>>16),(int)(tq.y&0xffff),(int)(tq.y>>16),
                   (int)(tq.z&0xffff),(int)(tq.z>>16),(int)(tq.w&0xffff),(int)(tq.w>>16)};
      #pragma unroll
      for(int i=0;i<8;i++)
        Af += sg[i] * (float)(acc[i] + 8*(ts[i] + (int)av[i]) - 4096);
    }
#else
    #pragma unroll
    for(int i=0;i<8;i++) Af += sg[i] * (float)acc[i];
#endif
    float D = rsc * Af + abar * rbr;
    nvd = fmaxf(D * eC * d_inv, 0.0f);

    // prefetch next emission
    int tn = (tt+1 < HT)? tt+1 : HT-1;
    mn = xls[tn];
    float eN = bf2f((unsigned)emTu[(size_t)mn*HN + j]);

    // [e] wave-local finalize: quantize vs wave max (DPP reduce), write plane wb
    float Mw = fmaxf(wmax_nn(nvd), 1e-30f);
    float sig = Mw * (1.0f/15.0f);
    int aq = __float2int_rn(nvd * (15.0f * rcpf(Mw)));
    float Sw = wsum_nn(nvd);
#if ENC_BIASED
    float AqSw = wsum_nn((float)aq);
#endif
    int aqn = xor1_i(aq);
    if((j&1)==0){
#if ENC_BIASED
      aplB[256*wb + (j>>1)] = (unsigned char)(((aq-8)&0xF) | (((aqn-8)&0xF)<<4));
#else
      aplB[256*wb + (j>>1)] = (unsigned char)((aq&0xF) | ((aqn&0xF)<<4));
#endif
    }
    if(L==0){
      sigS[8*wb+w] = sig; sumS[8*wb+w] = Sw;
#if ENC_BIASED
      aqS[8*wb+w] = AqSw;
#endif
    }
    eC = eN;
  }

  // ---- flush last step's S ----
  __syncthreads();
  {
    const int fb = (Tb & 1);
    float4 g0 = ((float4*)(sumS + 8*fb))[0], g1 = ((float4*)(sumS + 8*fb))[1];
    float Sf = ((g0.x+g0.y)+(g0.z+g0.w))+((g1.x+g1.y)+(g1.z+g1.w));
    if(t==0) out[b] = c_acc + __logf(Sf);
  }
}

extern "C" void kernel_launch(void* const* d_in, const int* in_sizes, int n_in,
                              void* d_out, int out_size, void* d_ws, size_t ws_size,
                              hipStream_t stream){
  const int*   x   = (const int*)d_in[0];
  const int*   T   = (const int*)d_in[1];
  const float* em  = (const float*)d_in[2];
  const float* tr  = (const float*)d_in[3];
  const float* pri = (const float*)d_in[4];
  float* out = (float*)d_out;

  char* ws = (char*)d_ws;
  float* em_lse = (float*)ws;                                   // 2 KiB
  float* P      = (float*)(ws + 2048);                          // 2 KiB
  float* pric   = (float*)(ws + 4096);                          // 16 B
  float* cmax   = (float*)(ws + 8192);                          // 2 KiB
  float* csum   = (float*)(ws + 10240);                         // 2 KiB
  float* rscale = (float*)(ws + 12288);                         // 2 KiB
  float* rbar   = (float*)(ws + 14336);                         // 2 KiB
  unsigned short* tsumq = (unsigned short*)(ws + 16384);        // 8 KiB
  unsigned short* emT = (unsigned short*)(ws + 24576);          // 4 MiB
  unsigned char*  TQ4 = (unsigned char*)(ws + 24576 + (size_t)HM*HN*2);  // 128 KiB

  k_prepA<<<1024, 512, 0, stream>>>(em, em_lse, tr, cmax, csum, pri, P, pric);
  k_prepB<<<1024, 512, 0, stream>>>(tr, cmax, csum, TQ4, rscale, rbar, tsumq,
                                    em, em_lse, emT);

  const int lds_bytes = 15104;
  (void)hipFuncSetAttribute((const void*)k_fwd, hipFuncAttributeMaxDynamicSharedMemorySize, lds_bytes);
  k_fwd<<<HB, 512, lds_bytes, stream>>>(x, T, emT, P, pric, rscale, rbar, tsumq,
                                        (const uint4*)TQ4, out);
}